// Round 4
// baseline (217.723 us; speedup 1.0000x reference)
//
#include <hip/hip_runtime.h>

#define NT 8
#define NY 32
#define NX 32
#define NN 1024  // NY*NX

typedef float v4f __attribute__((ext_vector_type(4)));

// Stencil coefficients of M = I + A for one node. c[(ry+1)*3+(rx+1)] is the
// coefficient toward target offset (ry,rx); zeroed when the TARGET node falls
// off-grid (matches reference `valid` masking on the column node).
__device__ __forceinline__ void node_coefs(const float* __restrict__ kap,
                                           const float* __restrict__ m,
                                           const float* __restrict__ H,
                                           const float* __restrict__ tau,
                                           int b, int node, int tc,
                                           int iy, int ix,
                                           float* c /*[9]*/, float& w) {
    const int base = node * NT + tc;                 // [.., node, t] layout, last dim NT
    const float kp  = kap[(b * NN) * NT + base];
    const float m1  = m[((b * 2 + 0) * NN) * NT + base];
    const float m2  = m[((b * 2 + 1) * NN) * NT + base];
    const float h11 = H[((b * 4 + 0) * NN) * NT + base];
    const float h12 = H[((b * 4 + 1) * NN) * NT + base];
    const float h22 = H[((b * 4 + 3) * NN) * NT + base];
    const float tv  = tau[(b * NN) * NT + base];
    w = 1.0f / (tv * tv);

    const float cxy = 0.5f * h12;
    const bool ym = iy > 0, yp = iy < NY - 1;
    const bool xm = ix > 0, xp = ix < NX - 1;

    c[4] = 1.0f + kp * kp + 2.0f * h11 + 2.0f * h22;
    c[0] = (ym && xm) ? -cxy               : 0.0f;
    c[1] =  ym        ? (-h22 - 0.5f * m2) : 0.0f;
    c[2] = (ym && xp) ?  cxy               : 0.0f;
    c[3] =  xm        ? (-h11 - 0.5f * m1) : 0.0f;
    c[5] =  xp        ? (-h11 + 0.5f * m1) : 0.0f;
    c[6] = (yp && xm) ?  cxy               : 0.0f;
    c[7] =  yp        ? (-h22 + 0.5f * m2) : 0.0f;
    c[8] = (yp && xp) ? -cxy               : 0.0f;
}

// One thread per (b,t,node). No LDS, no syncs. Inputs are L1/L2-hot (28 KB per
// (b,t) slice). Emits U[(bt,node)][9] = -w*c and D0[(bt,row)][25] = 5x5 window
// of M^T diag(w) M (+ w_next on center).
__global__ __launch_bounds__(256) void precompute_kernel(
        const float* __restrict__ kap, const float* __restrict__ m,
        const float* __restrict__ H, const float* __restrict__ tau,
        float* __restrict__ U, float* __restrict__ D0) {
    const int gtid = blockIdx.x * 256 + threadIdx.x;
    const int j  = gtid & (NN - 1);
    const int bt = gtid >> 10;
    const int b = bt >> 3, t = bt & 7;
    const int jy = j >> 5, jx = j & 31;

    float acc[25];
    #pragma unroll
    for (int q = 0; q < 25; ++q) acc[q] = 0.0f;

    #pragma unroll
    for (int d = 0; d < 9; ++d) {              // neighbor rows i = j + (ey,ex)
        const int ey = d / 3 - 1, ex = d % 3 - 1;
        const int iy = jy + ey, ix = jx + ex;
        if (iy >= 0 && iy < NY && ix >= 0 && ix < NX) {
            float c[9], w;
            node_coefs(kap, m, H, tau, b, iy * NX + ix, t, iy, ix, c, w);
            const float wmj = w * c[8 - d];    // w_i * M[i,j]
            #pragma unroll
            for (int r2 = 0; r2 < 9; ++r2) {   // column k = i + (ry,rx)
                const int ry = r2 / 3 - 1, rx = r2 % 3 - 1;
                acc[(ey + ry + 2) * 5 + (ex + rx + 2)] += wmj * c[r2];
            }
            if (d == 4) {                      // own node: emit U
                float* up = U + ((size_t)bt * NN + j) * 9;
                #pragma unroll
                for (int q = 0; q < 9; ++q) up[q] = -w * c[q];
            }
        }
    }
    if (t < NT - 1) {                          // diagonal: + w_{t+1}[j]
        const float tv = tau[((size_t)b * NN + j) * NT + (t + 1)];
        acc[12] += 1.0f / (tv * tv);
    }
    float* dp = D0 + ((size_t)bt * NN + j) * 25;
    #pragma unroll
    for (int q = 0; q < 25; ++q) dp[q] = acc[q];
}

// Grid-stride streaming writer. Each iteration: one group of 4 consecutive
// rows (same matrix, same jy); thread writes 4 coalesced float4s (one per row).
__global__ __launch_bounds__(256) void writer_kernel(
        const float* __restrict__ U, const float* __restrict__ D0,
        float* __restrict__ out, int ngroups) {
    const int tid = threadIdx.x;
    const int cy  = tid >> 3;            // column y of this thread's quad
    const int cx0 = (tid & 7) * 4;       // first column x
    const v4f z = {0.f, 0.f, 0.f, 0.f};

    for (int g = blockIdx.x; g < ngroups; g += gridDim.x) {
        const int row0 = g << 2;
        const int j0  = row0 & (NN - 1);         // multiple of 4 -> jy const, jx0<=28
        const int t   = (row0 >> 10) & 7;
        const int bb  = row0 >> 13;              // b*3 + blk
        const int blk = bb % 3;
        const int b   = bb / 3;
        const int jy = j0 >> 5, jx0 = j0 & 31;
        v4f* op = (v4f*)out + ((size_t)row0 << 8) + tid;

        if ((blk == 1 && t == 0) || (blk == 2 && t == NT - 1)) {
            __builtin_nontemporal_store(z, op);
            __builtin_nontemporal_store(z, op + 256);
            __builtin_nontemporal_store(z, op + 512);
            __builtin_nontemporal_store(z, op + 768);
            continue;
        }

        const int ddy = cy - jy;
        float v[16];
        #pragma unroll
        for (int q = 0; q < 16; ++q) v[q] = 0.0f;

        if (blk == 0) {
            if (ddy >= -2 && ddy <= 2) {
                const float* dbase = D0 + ((size_t)(b * NT + t) * NN + j0) * 25
                                        + (ddy + 2) * 5 + 2;
                #pragma unroll
                for (int r = 0; r < 4; ++r) {
                    const int jx = jx0 + r;
                    #pragma unroll
                    for (int qq = 0; qq < 4; ++qq) {
                        const int ddx = cx0 + qq - jx;
                        if (ddx >= -2 && ddx <= 2) v[r * 4 + qq] = dbase[r * 25 + ddx];
                    }
                }
            }
        } else if (blk == 1) {
            // lower[t][j][k] = -w_t[k] M_t[k,j] = U[(b,t,k)][8-off]
            if (ddy >= -1 && ddy <= 1) {
                const float* ub = U + (size_t)(b * NT + t) * NN * 9;
                #pragma unroll
                for (int r = 0; r < 4; ++r) {
                    const int jx = jx0 + r;
                    #pragma unroll
                    for (int qq = 0; qq < 4; ++qq) {
                        const int ddx = cx0 + qq - jx;
                        if (ddx >= -1 && ddx <= 1) {
                            const int k = cy * NX + cx0 + qq;
                            const int off = (ddy + 1) * 3 + (ddx + 1);
                            v[r * 4 + qq] = ub[(size_t)k * 9 + (8 - off)];
                        }
                    }
                }
            }
        } else {
            // upper[t][j][k] = -w_{t+1}[j] M_{t+1}[j,k] = U[(b,t+1,j)][off]
            if (ddy >= -1 && ddy <= 1) {
                const float* ub = U + ((size_t)(b * NT + t + 1) * NN + j0) * 9
                                    + (ddy + 1) * 3 + 1;
                #pragma unroll
                for (int r = 0; r < 4; ++r) {
                    const int jx = jx0 + r;
                    #pragma unroll
                    for (int qq = 0; qq < 4; ++qq) {
                        const int ddx = cx0 + qq - jx;
                        if (ddx >= -1 && ddx <= 1) v[r * 4 + qq] = ub[r * 9 + ddx];
                    }
                }
            }
        }

        {
            v4f a = {v[0], v[1], v[2], v[3]};
            v4f bq = {v[4], v[5], v[6], v[7]};
            v4f cq = {v[8], v[9], v[10], v[11]};
            v4f dq = {v[12], v[13], v[14], v[15]};
            __builtin_nontemporal_store(a,  op);
            __builtin_nontemporal_store(bq, op + 256);
            __builtin_nontemporal_store(cq, op + 512);
            __builtin_nontemporal_store(dq, op + 768);
        }
    }
}

extern "C" void kernel_launch(void* const* d_in, const int* in_sizes, int n_in,
                              void* d_out, int out_size, void* d_ws, size_t ws_size,
                              hipStream_t stream) {
    const float* kap = (const float*)d_in[0];  // [n_b,1,N,NT]
    const float* m   = (const float*)d_in[1];  // [n_b,2,N,NT]
    const float* H   = (const float*)d_in[2];  // [n_b,2,2,N,NT]
    const float* tau = (const float*)d_in[3];  // [n_b,1,N,NT]
    float* out = (float*)d_out;                // [n_b,3,NT,N,N]

    const int n_b = in_sizes[0] / (NN * NT);

    float* U  = (float*)d_ws;                              // n_b*NT*NN*9
    float* D0 = U + (size_t)n_b * NT * NN * 9;             // n_b*NT*NN*25

    precompute_kernel<<<n_b * NT * NN / 256, 256, 0, stream>>>(kap, m, H, tau, U, D0);

    const int ngroups = n_b * 3 * NT * NN / 4;             // 4-row groups
    const int grid = ngroups < 4096 ? ngroups : 4096;
    writer_kernel<<<grid, 256, 0, stream>>>(U, D0, out, ngroups);
}

// Round 5
// 199.292 us; speedup vs baseline: 1.0925x; 1.0925x over previous
//
#include <hip/hip_runtime.h>

#define NT 8
#define NY 32
#define NX 32
#define NN 1024  // NY*NX

// Stencil coefficients of M = I + A for one node. c[(ry+1)*3+(rx+1)] is the
// coefficient toward target offset (ry,rx); zeroed when the TARGET node falls
// off-grid (matches reference `valid` masking on the column node).
__device__ __forceinline__ void node_coefs(const float* __restrict__ kap,
                                           const float* __restrict__ m,
                                           const float* __restrict__ H,
                                           const float* __restrict__ tau,
                                           int b, int node, int tc,
                                           int iy, int ix,
                                           float* c /*[9]*/, float& w) {
    const int base = node * NT + tc;                 // [.., node, t] layout, last dim NT
    const float kp  = kap[(b * NN) * NT + base];
    const float m1  = m[((b * 2 + 0) * NN) * NT + base];
    const float m2  = m[((b * 2 + 1) * NN) * NT + base];
    const float h11 = H[((b * 4 + 0) * NN) * NT + base];
    const float h12 = H[((b * 4 + 1) * NN) * NT + base];
    const float h22 = H[((b * 4 + 3) * NN) * NT + base];
    const float tv  = tau[(b * NN) * NT + base];
    w = 1.0f / (tv * tv);

    const float cxy = 0.5f * h12;
    const bool ym = iy > 0, yp = iy < NY - 1;
    const bool xm = ix > 0, xp = ix < NX - 1;

    c[4] = 1.0f + kp * kp + 2.0f * h11 + 2.0f * h22;
    c[0] = (ym && xm) ? -cxy               : 0.0f;
    c[1] =  ym        ? (-h22 - 0.5f * m2) : 0.0f;
    c[2] = (ym && xp) ?  cxy               : 0.0f;
    c[3] =  xm        ? (-h11 - 0.5f * m1) : 0.0f;
    c[5] =  xp        ? (-h11 + 0.5f * m1) : 0.0f;
    c[6] = (yp && xm) ?  cxy               : 0.0f;
    c[7] =  yp        ? (-h22 + 0.5f * m2) : 0.0f;
    c[8] = (yp && xp) ? -cxy               : 0.0f;
}

// One block per (b, t, j). Computes time-t stencil coefs of j's 3x3 neighborhood
// once, then writes THREE output rows built from them:
//   D[t]       row j : 5x5 window of M_t^T diag(w_t) M_t  (+ w_{t+1}[j] on diag)
//   lower[t]   row j : -w_t[k] M_t[k,j]   (zeros when t==0)
//   upper[t-1] row j : -w_t[j] M_t[j,k]   (t>=1; block t==7 also zeros upper[7])
__global__ __launch_bounds__(256) void spde_kernel(const float* __restrict__ kap,
                                                   const float* __restrict__ m,
                                                   const float* __restrict__ H,
                                                   const float* __restrict__ tau,
                                                   float* __restrict__ out) {
    __shared__ float sc[9][9];   // sc[d][r]: coef of node j+off_d toward offset r
    __shared__ float sw[9];      // w_t at node j+off_d (0 if off-grid)
    __shared__ float valsD[25];
    __shared__ float valsL[9];
    __shared__ float valsU[9];

    const int gb = blockIdx.x;          // ((b*NT)+t)*NN + j
    const int j  = gb & (NN - 1);
    const int bt = gb >> 10;
    const int t  = bt & 7;
    const int b  = bt >> 3;
    const int jy = j >> 5, jx = j & 31;
    const int tid = threadIdx.x;

    if (tid < 9) {  // phase 0: stencil coefs of the 9 neighborhood nodes at time t
        const int ey = tid / 3 - 1, ex = tid % 3 - 1;
        const int iy = jy + ey, ix = jx + ex;
        float c[9];
        float w = 0.0f;
        if (iy >= 0 && iy < NY && ix >= 0 && ix < NX) {
            node_coefs(kap, m, H, tau, b, iy * NX + ix, t, iy, ix, c, w);
        } else {
            #pragma unroll
            for (int q = 0; q < 9; ++q) c[q] = 0.0f;
        }
        #pragma unroll
        for (int q = 0; q < 9; ++q) sc[tid][q] = c[q];
        sw[tid] = w;
    }
    __syncthreads();

    if (tid < 25) {          // D window
        const int dy = tid / 5 - 2, dx = tid % 5 - 2;
        float acc = 0.0f;
        #pragma unroll
        for (int d = 0; d < 9; ++d) {    // rows i = j + off_d
            const int ey = d / 3 - 1, ex = d % 3 - 1;
            const int r2y = dy - ey, r2x = dx - ex;
            if (r2y >= -1 && r2y <= 1 && r2x >= -1 && r2x <= 1) {
                acc += sw[d] * sc[d][8 - d] * sc[d][(r2y + 1) * 3 + (r2x + 1)];
            }
        }
        if (tid == 12 && t < NT - 1) {   // diagonal: + w_{t+1}[j]
            const float tv = tau[((size_t)b * NN + j) * NT + (t + 1)];
            acc += 1.0f / (tv * tv);
        }
        valsD[tid] = acc;
    } else if (tid >= 64 && tid < 73) {  // lower[t]: -w_t[k] M_t[k,j]
        const int d = tid - 64;
        valsL[d] = -sw[d] * sc[d][8 - d];
    } else if (tid >= 73 && tid < 82) {  // upper[t-1]: -w_t[j] M_t[j,k]
        const int q = tid - 73;
        valsU[q] = -sw[4] * sc[4][q];
    }
    __syncthreads();

    // store phase: each thread owns columns 4*tid..4*tid+3 of each row
    const int cy  = tid >> 3;
    const int cx0 = (tid & 7) * 4;
    const int ddy = cy - jy;
    float4* const outq = (float4*)out;
    const size_t rowq = ((size_t)j << 8) + tid;   // quad index within a matrix row set
    const size_t matD = ((size_t)(b * 3 + 0) * NT + t) << 18;      // NN*NN/4 quads
    const size_t matL = ((size_t)(b * 3 + 1) * NT + t) << 18;

    // D row
    {
        float4 v = make_float4(0.f, 0.f, 0.f, 0.f);
        if (ddy >= -2 && ddy <= 2) {
            float* vp = &v.x;
            const float* wrow = &valsD[(ddy + 2) * 5 + 2];
            #pragma unroll
            for (int qq = 0; qq < 4; ++qq) {
                const int ddx = cx0 + qq - jx;
                if (ddx >= -2 && ddx <= 2) vp[qq] = wrow[ddx];
            }
        }
        outq[matD + rowq] = v;
    }
    // lower[t] row (zeros when t == 0)
    {
        float4 v = make_float4(0.f, 0.f, 0.f, 0.f);
        if (t > 0 && ddy >= -1 && ddy <= 1) {
            float* vp = &v.x;
            const float* wrow = &valsL[(ddy + 1) * 3 + 1];
            #pragma unroll
            for (int qq = 0; qq < 4; ++qq) {
                const int ddx = cx0 + qq - jx;
                if (ddx >= -1 && ddx <= 1) vp[qq] = wrow[ddx];
            }
        }
        outq[matL + rowq] = v;
    }
    // upper[t-1] row (t >= 1); block t==7 also writes upper[7] zeros
    if (t >= 1) {
        const size_t matU = ((size_t)(b * 3 + 2) * NT + (t - 1)) << 18;
        float4 v = make_float4(0.f, 0.f, 0.f, 0.f);
        if (ddy >= -1 && ddy <= 1) {
            float* vp = &v.x;
            const float* wrow = &valsU[(ddy + 1) * 3 + 1];
            #pragma unroll
            for (int qq = 0; qq < 4; ++qq) {
                const int ddx = cx0 + qq - jx;
                if (ddx >= -1 && ddx <= 1) vp[qq] = wrow[ddx];
            }
        }
        outq[matU + rowq] = v;
        if (t == NT - 1) {
            const size_t matU7 = ((size_t)(b * 3 + 2) * NT + 7) << 18;
            outq[matU7 + rowq] = make_float4(0.f, 0.f, 0.f, 0.f);
        }
    }
}

extern "C" void kernel_launch(void* const* d_in, const int* in_sizes, int n_in,
                              void* d_out, int out_size, void* d_ws, size_t ws_size,
                              hipStream_t stream) {
    const float* kap = (const float*)d_in[0];  // [n_b,1,N,NT]
    const float* m   = (const float*)d_in[1];  // [n_b,2,N,NT]
    const float* H   = (const float*)d_in[2];  // [n_b,2,2,N,NT]
    const float* tau = (const float*)d_in[3];  // [n_b,1,N,NT]
    float* out = (float*)d_out;                // [n_b,3,NT,N,N]

    const int n_b = in_sizes[0] / (NN * NT);
    const int grid = n_b * NT * NN;            // one block per (b,t,node)
    spde_kernel<<<grid, 256, 0, stream>>>(kap, m, H, tau, out);
}